// Round 24
// baseline (197.027 us; speedup 1.0000x reference)
//
#include <hip/hip_runtime.h>

// Problem constants
#define B_    8
#define H_    512
#define W_    512
#define KK_   9
#define COUT_ 3
#define HO_   510
#define WO_   510
#define PLANE_ 260100           // HO_*WO_

// Tile: 4 output rows x 256 cols per block (512 threads, 2 px/thread).
// LDS window: rows [ho0-8, ho0+13] (22), cols [cb-8, cb+267] (276),
// ZERO-extended outside the image -> fast path needs no validity/clamp math.
#define TR_    4
#define XROWS_ 22
#define XCOLS_ 276
#define NCHK_  69               // XCOLS_/4 float4 chunks per row

typedef float f2 __attribute__((ext_vector_type(2)));

__device__ __forceinline__ int iclamp(int v, int lo, int hi) {
    return v < lo ? lo : (v > hi ? hi : v);
}

__global__ __launch_bounds__(512, 4) void dcn_fwd_kernel(
    const float* __restrict__ x,       // [B,1,512,512]
    const float* __restrict__ offset,  // [B,18,510,510]
    const float* __restrict__ mask,    // [B,9,510,510]
    const float* __restrict__ weight,  // [3,1,3,3]
    const float* __restrict__ bias,    // [3]
    float* __restrict__ out)           // [B,3,510,510]
{
    __shared__ float sx[XROWS_ * XCOLS_];   // 24,288 B

    const int bid  = blockIdx.x;       // 2 colblk * 128 band * 8 batch = 2048
    const int wt   = bid & 1;          // col-block (256 cols)
    const int band = (bid >> 1) & 127; // row band (4 rows)
    const int b    = bid >> 8;         // batch

    const int ho0 = band * TR_;        // 0..508
    const int cb  = wt * 256;          // output col base
    const int XR0 = ho0 - 8;           // window row 0 = image row XR0
    const int XC0 = cb - 8;            // window col 0 = image col XC0

    const float* xb = x + (b << 18);

    // ---- stage zero-extended x window (all chunks are whole: in or out) ----
    for (int i = threadIdx.x; i < XROWS_ * NCHK_; i += 512) {
        const int wr  = i / NCHK_;
        const int ck  = i - wr * NCHK_;
        const int yr  = XR0 + wr;
        const int col = XC0 + 4 * ck;  // image col of chunk start (mult of 4)
        float4 v = make_float4(0.f, 0.f, 0.f, 0.f);
        if (((unsigned)yr < 512u) & ((unsigned)col <= 508u))
            v = *(const float4*)(xb + (yr << 9) + col);
        *(float4*)(&sx[wr * XCOLS_ + 4 * ck]) = v;
    }
    __syncthreads();

    // ---- output mapping: 2 px/thread ----
    const int tid = threadIdx.x;
    const int r   = tid >> 7;          // 0..3
    const int c   = tid & 127;         // 0..127
    int ho = ho0 + r;
    const bool vrow = (ho < HO_);
    if (!vrow) ho = HO_ - 1;           // clamp for safe loads; stores predicated
    int wo0 = cb + 2 * c;
    if (wo0 > WO_ - 2) wo0 = WO_ - 2;  // duplicate last pair (benign)

    const int pix = ho * WO_ + wo0;    // even -> f2 streams 8B aligned
    const float* offb = offset + b * (2 * KK_ * PLANE_) + pix;
    const float* mb   = mask   + b * (KK_ * PLANE_)    + pix;

    // weights/bias: uniform addresses -> scalar broadcast loads
    float w0[KK_], w1[KK_], w2[KK_];
    #pragma unroll
    for (int k = 0; k < KK_; ++k) {
        w0[k] = weight[0 * KK_ + k];
        w1[k] = weight[1 * KK_ + k];
        w2[k] = weight[2 * KK_ + k];
    }
    const float b0 = bias[0], b1 = bias[1], b2 = bias[2];

    const float fho = (float)ho;
    const float fwo = (float)wo0;

    float a00 = 0.f, a01 = 0.f;
    float a10 = 0.f, a11 = 0.f;
    float a20 = 0.f, a21 = 0.f;

    #pragma unroll
    for (int kh = 0; kh < 3; ++kh) {
        #pragma unroll
        for (int kw = 0; kw < 3; ++kw) {
            const int kk = kh * 3 + kw;
            const f2 dy2 = *(const f2*)(offb + (2 * kk)     * PLANE_);
            const f2 dx2 = *(const f2*)(offb + (2 * kk + 1) * PLANE_);
            const f2 m2  = *(const f2*)(mb   +  kk          * PLANE_);

            #pragma unroll
            for (int p = 0; p < 2; ++p) {
                const float py = (fho + (float)kh) + dy2[p];
                const float px = (fwo + (float)(kw + p)) + dx2[p];

                const float y0f = floorf(py);
                const float x0f = floorf(px);
                const float ly  = py - y0f;
                const float lx  = px - x0f;

                const int iy = (int)y0f - XR0;   // window row of top corners
                const int ix = (int)x0f - XC0;   // window col of left corners

                float v00, v01, v10, v11;
                if (__builtin_expect(((unsigned)iy <= (unsigned)(XROWS_ - 2)) &
                                     ((unsigned)ix <= (unsigned)(XCOLS_ - 2)), 1)) {
                    // window is the zero-extended image: pure bilinear, no
                    // validity/clamp math. adjacent dwords -> ds_read2_b32.
                    const int a = iy * XCOLS_ + ix;
                    v00 = sx[a];
                    v01 = sx[a + 1];
                    v10 = sx[a + XCOLS_];
                    v11 = sx[a + XCOLS_ + 1];
                } else {
                    // |offset| > ~8: essentially never; full reference semantics
                    const float y1f = y0f + 1.0f, x1f = x0f + 1.0f;
                    const float vy0 = (y0f >= 0.f && y0f <= 511.f) ? 1.f : 0.f;
                    const float vy1 = (y1f >= 0.f && y1f <= 511.f) ? 1.f : 0.f;
                    const float vx0 = (x0f >= 0.f && x0f <= 511.f) ? 1.f : 0.f;
                    const float vx1 = (x1f >= 0.f && x1f <= 511.f) ? 1.f : 0.f;
                    const int yi0 = iclamp((int)y0f, 0, 511);
                    const int yi1 = iclamp((int)y0f + 1, 0, 511);
                    const int xi0 = iclamp((int)x0f, 0, 511);
                    const int xi1 = iclamp((int)x0f + 1, 0, 511);
                    v00 = xb[(yi0 << 9) + xi0] * (vy0 * vx0);
                    v01 = xb[(yi0 << 9) + xi1] * (vy0 * vx1);
                    v10 = xb[(yi1 << 9) + xi0] * (vy1 * vx0);
                    v11 = xb[(yi1 << 9) + xi1] * (vy1 * vx1);
                }

                const float top = fmaf(lx, v01 - v00, v00);
                const float bot = fmaf(lx, v11 - v10, v10);
                const float val = fmaf(ly, bot - top, top);
                const float s   = val * m2[p];

                if (p == 0) {
                    a00 = fmaf(w0[kk], s, a00);
                    a10 = fmaf(w1[kk], s, a10);
                    a20 = fmaf(w2[kk], s, a20);
                } else {
                    a01 = fmaf(w0[kk], s, a01);
                    a11 = fmaf(w1[kk], s, a11);
                    a21 = fmaf(w2[kk], s, a21);
                }
            }
        }
    }

    if (vrow) {
        const int ob = b * (COUT_ * PLANE_) + pix;
        f2 o0 = {a00 + b0, a01 + b0};
        f2 o1 = {a10 + b1, a11 + b1};
        f2 o2 = {a20 + b2, a21 + b2};
        *(f2*)(out + ob)              = o0;
        *(f2*)(out + ob + PLANE_)     = o1;
        *(f2*)(out + ob + 2 * PLANE_) = o2;
    }
}

extern "C" void kernel_launch(void* const* d_in, const int* in_sizes, int n_in,
                              void* d_out, int out_size, void* d_ws, size_t ws_size,
                              hipStream_t stream) {
    const float* x      = (const float*)d_in[0];
    const float* offset = (const float*)d_in[1];
    const float* mask   = (const float*)d_in[2];
    const float* weight = (const float*)d_in[3];
    const float* bias   = (const float*)d_in[4];
    float* out = (float*)d_out;

    const int grid = 2 * 128 * B_;   // colblk x band x batch = 2048
    dcn_fwd_kernel<<<grid, 512, 0, stream>>>(x, offset, mask, weight, bias, out);
}

// Round 25
// 52.857 us; speedup vs baseline: 3.7276x; 3.7276x over previous
//
#include <hip/hip_runtime.h>

// Problem constants
#define B_    8
#define H_    512
#define W_    512
#define KK_   9
#define COUT_ 3
#define HO_   510
#define WO_   510
#define PLANE_ 260100           // HO_*WO_

__device__ __forceinline__ int iclamp(int v, int lo, int hi) {
    return v < lo ? lo : (v > hi ? hi : v);
}

typedef float f2  __attribute__((ext_vector_type(2)));
typedef float f2a __attribute__((ext_vector_type(2), aligned(4)));

// Best-known kernel (R19, 52.9 us):
//  - 2D wave clustering: wave = 4 rows x 32 cols output patch (R14, +13%)
//  - fused horizontal corner-pair gathers: one 8B load per corner row (R16, +12%)
//  - 2 px/thread with f2 streams/stores + sched_barrier(0) between the two
//    pixel bodies to stop the compiler pipelining both pixels' gather state
//    (R17's VGPR-64/occupancy-39% failure mode) (R19, +8%)
// Structural floor: 18 irreducible divergent gathers/px through the TA pipe
// (~43 us intercept); HBM ~20%, VALU ~30% -> neither is the binding resource.
__global__ __launch_bounds__(512, 4) void dcn_fwd_kernel(
    const float* __restrict__ x,       // [B,1,512,512]
    const float* __restrict__ offset,  // [B,18,510,510]
    const float* __restrict__ mask,    // [B,9,510,510]
    const float* __restrict__ weight,  // [3,1,3,3]
    const float* __restrict__ bias,    // [3]
    float* __restrict__ out)           // [B,3,510,510]
{
    const int bid  = blockIdx.x;       // 2 colblk * 128 band * 8 batch = 2048
    const int wt   = bid & 1;          // col-block (256 cols)
    const int band = (bid >> 1) & 127; // row band (4 rows)
    const int b    = bid >> 8;         // batch

    const int tid  = threadIdx.x;
    const int wave = tid >> 6;         // 0..7
    const int lane = tid & 63;
    const int r    = lane >> 4;        // 0..3
    const int c    = lane & 15;        // 0..15

    int ho = band * 4 + r;             // 0..511
    const bool vrow = (ho < HO_);
    if (!vrow) ho = HO_ - 1;           // clamp for safe loads; stores predicated
    int wo0 = wt * 256 + wave * 32 + 2 * c;   // 0..510, even
    if (wo0 > WO_ - 2) wo0 = WO_ - 2;  // duplicate last pair (benign)

    const int pix = ho * WO_ + wo0;    // even -> f2 streams 8B aligned
    const float* xb   = x + (b << 18);
    const float* offb = offset + b * (2 * KK_ * PLANE_) + pix;
    const float* mb   = mask   + b * (KK_ * PLANE_)    + pix;

    // weights/bias: uniform addresses -> scalar broadcast loads
    float w0[KK_], w1[KK_], w2[KK_];
    #pragma unroll
    for (int k = 0; k < KK_; ++k) {
        w0[k] = weight[0 * KK_ + k];
        w1[k] = weight[1 * KK_ + k];
        w2[k] = weight[2 * KK_ + k];
    }
    const float b0 = bias[0], b1 = bias[1], b2 = bias[2];

    const float fho = (float)ho;
    const float fwo = (float)wo0;

    float a00 = 0.f, a01 = 0.f;   // cout0 px{0,1}
    float a10 = 0.f, a11 = 0.f;
    float a20 = 0.f, a21 = 0.f;

    #pragma unroll
    for (int kh = 0; kh < 3; ++kh) {
        #pragma unroll
        for (int kw = 0; kw < 3; ++kw) {
            const int kk = kh * 3 + kw;
            const f2 dy2 = *(const f2*)(offb + (2 * kk)     * PLANE_);
            const f2 dx2 = *(const f2*)(offb + (2 * kk + 1) * PLANE_);
            const f2 m2  = *(const f2*)(mb   +  kk          * PLANE_);

            #pragma unroll
            for (int p = 0; p < 2; ++p) {
                const float py = (fho + (float)kh) + dy2[p];
                const float px = (fwo + (float)(kw + p)) + dx2[p];

                const float y0f = floorf(py);
                const float x0f = floorf(px);
                const float ly  = py - y0f;
                const float lx  = px - x0f;
                const float y1f = y0f + 1.0f;
                const float x1f = x0f + 1.0f;

                // validity on UNCLIPPED float corner coords (reference semantics)
                const float vy0 = (y0f >= 0.f && y0f <= 511.f) ? 1.f : 0.f;
                const float vy1 = (y1f >= 0.f && y1f <= 511.f) ? 1.f : 0.f;
                const float vx0 = (x0f >= 0.f && x0f <= 511.f) ? 1.f : 0.f;
                const float vx1 = (x1f >= 0.f && x1f <= 511.f) ? 1.f : 0.f;

                const int iy0 = (int)y0f;
                const int ix0 = (int)x0f;
                const int yi0 = iclamp(iy0,     0, 511);
                const int yi1 = iclamp(iy0 + 1, 0, 511);
                const int xc0 = iclamp(ix0,     0, 510);  // pair {xc0,xc0+1} in-bounds

                // one 8B load per row covers both horizontal corners (R16)
                const f2a q0 = *(const f2a*)(xb + (yi0 << 9) + xc0);
                const f2a q1 = *(const f2a*)(xb + (yi1 << 9) + xc0);

                const bool hi = (x0f >= 511.f);
                const bool lo = (x0f < 0.f);

                const float v00 = (hi ? q0.y : q0.x) * (vy0 * vx0);
                const float v01 = (lo ? q0.x : q0.y) * (vy0 * vx1);
                const float v10 = (hi ? q1.y : q1.x) * (vy1 * vx0);
                const float v11 = (lo ? q1.x : q1.y) * (vy1 * vx1);

                const float top = fmaf(lx, v01 - v00, v00);
                const float bot = fmaf(lx, v11 - v10, v10);
                const float val = fmaf(ly, bot - top, top);
                const float s   = val * m2[p];

                if (p == 0) {
                    a00 = fmaf(w0[kk], s, a00);
                    a10 = fmaf(w1[kk], s, a10);
                    a20 = fmaf(w2[kk], s, a20);
                    // wall between pixel 0 and pixel 1: forbids pipelining both
                    // pixels' gather state (R17's VGPR-64 failure mode)
                    __builtin_amdgcn_sched_barrier(0);
                } else {
                    a01 = fmaf(w0[kk], s, a01);
                    a11 = fmaf(w1[kk], s, a11);
                    a21 = fmaf(w2[kk], s, a21);
                }
            }
        }
    }

    if (vrow) {
        const int ob = b * (COUT_ * PLANE_) + pix;
        f2 o0 = {a00 + b0, a01 + b0};
        f2 o1 = {a10 + b1, a11 + b1};
        f2 o2 = {a20 + b2, a21 + b2};
        *(f2*)(out + ob)              = o0;
        *(f2*)(out + ob + PLANE_)     = o1;
        *(f2*)(out + ob + 2 * PLANE_) = o2;
    }
}

extern "C" void kernel_launch(void* const* d_in, const int* in_sizes, int n_in,
                              void* d_out, int out_size, void* d_ws, size_t ws_size,
                              hipStream_t stream) {
    const float* x      = (const float*)d_in[0];
    const float* offset = (const float*)d_in[1];
    const float* mask   = (const float*)d_in[2];
    const float* weight = (const float*)d_in[3];
    const float* bias   = (const float*)d_in[4];
    float* out = (float*)d_out;

    const int grid = 2 * 128 * B_;   // colblk x band x batch = 2048
    dcn_fwd_kernel<<<grid, 512, 0, stream>>>(x, offset, mask, weight, bias, out);
}